// Round 1
// baseline (257.309 us; speedup 1.0000x reference)
//
#include <hip/hip_runtime.h>
#include <hip/hip_bf16.h>

#define NN 8192
#define DD 128
#define LDST 72   // LDS row stride in bf16 elements for a 64-wide K half (+8 pad)

using bf16x8 = __attribute__((ext_vector_type(8))) short;
using f32x4  = __attribute__((ext_vector_type(4))) float;

// ---------------- kernel 1: row norms + diagonal logit_p ----------------
__global__ __launch_bounds__(256) void k_norms(const float* __restrict__ enc,
                                               const float* __restrict__ dec,
                                               float* __restrict__ en,
                                               float* __restrict__ dn,
                                               float* __restrict__ logit_p) {
  int row  = blockIdx.x * 4 + (threadIdx.x >> 6);
  int lane = threadIdx.x & 63;
  float2 ev = reinterpret_cast<const float2*>(enc)[row * 64 + lane];
  float2 dv = reinterpret_cast<const float2*>(dec)[row * 64 + lane];
  float se = ev.x * ev.x + ev.y * ev.y;
  float sd = dv.x * dv.x + dv.y * dv.y;
  float sp = ev.x * dv.x + ev.y * dv.y;
#pragma unroll
  for (int off = 32; off; off >>= 1) {
    se += __shfl_down(se, off);
    sd += __shfl_down(sd, off);
    sp += __shfl_down(sp, off);
  }
  if (lane == 0) {
    float a = sqrtf(se), b = sqrtf(sd);
    en[row] = a;
    dn[row] = b;
    float s  = sp / (a * b + 1e-5f);
    float ap = fmaxf(1.25f - s, 0.0f);
    logit_p[row] = -ap * (s - 0.75f) * 64.0f;
  }
}

// ---------------- kernel 2: main tiled GEMM + fused diagonal sumexp ----------------
__global__ __launch_bounds__(256, 3) void k_main(const float* __restrict__ enc,
                                                 const float* __restrict__ dec,
                                                 const float* __restrict__ en,
                                                 const float* __restrict__ dn,
                                                 float* __restrict__ sumexp) {
  __shared__ __align__(16) unsigned short As[128 * LDST];
  __shared__ __align__(16) unsigned short Bs[128 * LDST];
  __shared__ float enL[128];
  __shared__ float dnL[128];
  __shared__ float diag[256];

  const int t  = threadIdx.x;
  const int bx = blockIdx.x, by = blockIdx.y;
  const int i0 = by * 128, j0 = bx * 128;

  diag[t] = 0.0f;
  if (t < 128) enL[t] = en[i0 + t];
  else         dnL[t - 128] = dn[j0 + t - 128];

  const int c4h = t & 15;   // float4 index within the 64-col K half
  const int r0  = t >> 4;   // 0..15

  const int lane = t & 63;
  const int w = t >> 6, wrow = w >> 1, wcol = w & 1;
  const int l15 = lane & 15, quad = lane >> 4;

  f32x4 acc[4][4];
  const f32x4 zv = {0.f, 0.f, 0.f, 0.f};
#pragma unroll
  for (int r = 0; r < 4; ++r)
#pragma unroll
    for (int c = 0; c < 4; ++c) acc[r][c] = zv;

  const unsigned short* Ap = &As[(wrow * 64 + l15) * LDST + quad * 8];
  const unsigned short* Bp = &Bs[(wcol * 64 + l15) * LDST + quad * 8];

#pragma unroll
  for (int kh = 0; kh < 2; ++kh) {
    if (kh) __syncthreads();  // previous compute must finish before restage
    // stage K-half kh: fp32 global -> bf16 LDS
#pragma unroll
    for (int it = 0; it < 8; ++it) {
      int row = r0 + it * 16;
      float4 va = reinterpret_cast<const float4*>(enc)[(i0 + row) * 32 + kh * 16 + c4h];
      float4 vb = reinterpret_cast<const float4*>(dec)[(j0 + row) * 32 + kh * 16 + c4h];
      union { __hip_bfloat162 h; unsigned int u; } pa0, pa1, pb0, pb1;
      pa0.h = __float22bfloat162_rn(make_float2(va.x, va.y));
      pa1.h = __float22bfloat162_rn(make_float2(va.z, va.w));
      pb0.h = __float22bfloat162_rn(make_float2(vb.x, vb.y));
      pb1.h = __float22bfloat162_rn(make_float2(vb.z, vb.w));
      uint2 ua; ua.x = pa0.u; ua.y = pa1.u;
      uint2 ub; ub.x = pb0.u; ub.y = pb1.u;
      *reinterpret_cast<uint2*>(&As[row * LDST + c4h * 4]) = ua;
      *reinterpret_cast<uint2*>(&Bs[row * LDST + c4h * 4]) = ub;
    }
    __syncthreads();
    // compute this K half: 2 MFMA k-steps of 32
#pragma unroll
    for (int k0 = 0; k0 < 64; k0 += 32) {
      bf16x8 a[4], b[4];
#pragma unroll
      for (int r = 0; r < 4; ++r)
        a[r] = *reinterpret_cast<const bf16x8*>(Ap + r * 16 * LDST + k0);
#pragma unroll
      for (int c = 0; c < 4; ++c)
        b[c] = *reinterpret_cast<const bf16x8*>(Bp + c * 16 * LDST + k0);
#pragma unroll
      for (int r = 0; r < 4; ++r)
#pragma unroll
        for (int c = 0; c < 4; ++c)
          acc[r][c] = __builtin_amdgcn_mfma_f32_16x16x32_bf16(a[r], b[c], acc[r][c], 0, 0, 0);
    }
  }

  // ---------------- epilogue: fused circle-loss exp + per-diagonal reduce ----------------
  float enr[4][4];
#pragma unroll
  for (int r = 0; r < 4; ++r)
#pragma unroll
    for (int g = 0; g < 4; ++g)
      enr[r][g] = enL[wrow * 64 + r * 16 + quad * 4 + g];
  float dnc[4];
#pragma unroll
  for (int c = 0; c < 4; ++c) dnc[c] = dnL[wcol * 64 + c * 16 + l15];

  const bool hasDiag = (bx == by);
  // diagonal (col-row) of this lane's elements, offset to [0,254]; depends only on (c-r, reg)
  const int dbase = (wcol - wrow) * 64 + (l15 - quad * 4) + 127;

  // constants: 64*log2(e) = 92.33248262 ; 0.25*64*log2(e) = 23.08312065
#pragma unroll
  for (int dlt = -3; dlt <= 3; ++dlt) {
#pragma unroll
    for (int g = 0; g < 4; ++g) {
      float s = 0.0f;
#pragma unroll
      for (int r = 0; r < 4; ++r) {
        int c = r + dlt;
        if (c < 0 || c > 3) continue;
        float dot = acc[r][c][g];
        float rn  = __builtin_amdgcn_rcpf(fmaf(enr[r][g], dnc[c], 1e-5f));
        float sn  = dot * rn;
        float an  = fmaxf(sn + 0.25f, 0.0f);
        float u   = fmaf(sn, 92.332483f, -23.083121f); // (sn-0.25)*64*log2e
        s += exp2f(an * u);
      }
      int ld = dbase + dlt * 16 - g;
      if (hasDiag && (ld == 127)) s = 0.0f;  // exclude true diagonal (sp handled separately)
      unsafeAtomicAdd(&diag[ld], s);
    }
  }
  __syncthreads();

  // flush the 255 per-tile diagonal partials to the global per-diagonal sums
  if (t < 255) {
    int d = (j0 - i0 + t - 127 + NN) & (NN - 1);
    unsafeAtomicAdd(&sumexp[d], diag[t]);
  }
}

// ---------------- kernel 3: lse_p + final softplus mean ----------------
__global__ __launch_bounds__(256) void k_final(const float* __restrict__ logit_p,
                                               const float* __restrict__ sumexp,
                                               float* __restrict__ out) {
  __shared__ float sm[4];
  const int t = threadIdx.x;
  const int lane = t & 63, wv = t >> 6;

  // phase 1: max of logit_p
  float m = -3.0e38f;
  for (int i = t; i < NN; i += 256) m = fmaxf(m, logit_p[i]);
#pragma unroll
  for (int off = 32; off; off >>= 1) m = fmaxf(m, __shfl_down(m, off));
  if (lane == 0) sm[wv] = m;
  __syncthreads();
  m = fmaxf(fmaxf(sm[0], sm[1]), fmaxf(sm[2], sm[3]));
  __syncthreads();

  // phase 2: shifted sumexp -> lse_p
  float s = 0.0f;
  for (int i = t; i < NN; i += 256) s += __expf(logit_p[i] - m);
#pragma unroll
  for (int off = 32; off; off >>= 1) s += __shfl_down(s, off);
  if (lane == 0) sm[wv] = s;
  __syncthreads();
  s = sm[0] + sm[1] + sm[2] + sm[3];
  float lse_p = m + __logf(s);
  __syncthreads();

  // phase 3: mean over d=1..N-1 of softplus(log(sumexp[d]) + lse_p)
  float acc = 0.0f;
  for (int i = t; i < NN; i += 256) {
    if (i == 0) continue;
    float x = __logf(sumexp[i]) + lse_p;
    acc += fmaxf(x, 0.0f) + log1pf(__expf(-fabsf(x)));
  }
#pragma unroll
  for (int off = 32; off; off >>= 1) acc += __shfl_down(acc, off);
  if (lane == 0) sm[wv] = acc;
  __syncthreads();
  if (t == 0) out[0] = (sm[0] + sm[1] + sm[2] + sm[3]) * (1.0f / 8191.0f);
}

// ---------------- launcher ----------------
extern "C" void kernel_launch(void* const* d_in, const int* in_sizes, int n_in,
                              void* d_out, int out_size, void* d_ws, size_t ws_size,
                              hipStream_t stream) {
  const float* enc = (const float*)d_in[0];
  const float* dec = (const float*)d_in[1];
  float* ws = (float*)d_ws;
  float* en      = ws;               // 8192
  float* dn      = ws + NN;          // 8192
  float* logit_p = ws + 2 * NN;      // 8192
  float* sumexp  = ws + 3 * NN;      // 8192
  float* out = (float*)d_out;

  hipMemsetAsync(sumexp, 0, NN * sizeof(float), stream);
  k_norms<<<NN / 4, 256, 0, stream>>>(enc, dec, en, dn, logit_p);
  dim3 grid(NN / 128, NN / 128);
  k_main<<<grid, 256, 0, stream>>>(enc, dec, en, dn, sumexp);
  k_final<<<1, 256, 0, stream>>>(logit_p, sumexp, out);
}

// Round 2
// 256.112 us; speedup vs baseline: 1.0047x; 1.0047x over previous
//
#include <hip/hip_runtime.h>
#include <hip/hip_bf16.h>

#define NN 8192

using bf16x8 = __attribute__((ext_vector_type(8))) short;
using f32x4  = __attribute__((ext_vector_type(4))) float;

// ---- async global->LDS 16B (wave-uniform base + lane*16 layout) ----
__device__ __forceinline__ void gl_lds16(const void* g, void* l) {
  __builtin_amdgcn_global_load_lds(
      (const __attribute__((address_space(1))) unsigned int*)(unsigned long long)g,
      (__attribute__((address_space(3))) unsigned int*)(unsigned int)(unsigned long long)l,
      16, 0, 0);
}

// ---- order-preserving float<->uint encode for atomicMax on floats ----
__device__ __forceinline__ unsigned fenc(float f) {
  unsigned u = __float_as_uint(f);
  return (u & 0x80000000u) ? ~u : (u | 0x80000000u);
}
__device__ __forceinline__ float fdec(unsigned u) {
  return __uint_as_float((u & 0x80000000u) ? (u & 0x7fffffffu) : ~u);
}

// ---------------- kernel 1: normalize rows -> bf16, logit_p, global max ----------------
__global__ __launch_bounds__(256) void k_prep(const float* __restrict__ enc,
                                              const float* __restrict__ dec,
                                              unsigned* __restrict__ Abf,
                                              unsigned* __restrict__ Bbf,
                                              float* __restrict__ logit_p,
                                              unsigned* __restrict__ mkey) {
  __shared__ float wmax[4];
  const int w = threadIdx.x >> 6, lane = threadIdx.x & 63;
  const int row = blockIdx.x * 4 + w;
  float2 ev = reinterpret_cast<const float2*>(enc)[row * 64 + lane];
  float2 dv = reinterpret_cast<const float2*>(dec)[row * 64 + lane];
  float se = ev.x * ev.x + ev.y * ev.y;
  float sd = dv.x * dv.x + dv.y * dv.y;
  float sp = ev.x * dv.x + ev.y * dv.y;
#pragma unroll
  for (int off = 1; off < 64; off <<= 1) {
    se += __shfl_xor(se, off);
    sd += __shfl_xor(sd, off);
    sp += __shfl_xor(sp, off);
  }
  float ie = rsqrtf(se), id = rsqrtf(sd);
  union { __hip_bfloat162 h; unsigned u; } pa, pb;
  pa.h = __float22bfloat162_rn(make_float2(ev.x * ie, ev.y * ie));
  pb.h = __float22bfloat162_rn(make_float2(dv.x * id, dv.y * id));
  Abf[row * 64 + lane] = pa.u;
  Bbf[row * 64 + lane] = pb.u;
  if (lane == 0) {
    float en = se * ie, dn = sd * id;                 // sqrt via x*rsqrt(x)
    float s  = sp / (en * dn + 1e-5f);
    float lp = -fmaxf(1.25f - s, 0.0f) * (s - 0.75f) * 64.0f;
    logit_p[row] = lp;
    wmax[w] = lp;
  }
  __syncthreads();
  if (threadIdx.x == 0) {
    float m = fmaxf(fmaxf(wmax[0], wmax[1]), fmaxf(wmax[2], wmax[3]));
    atomicMax(mkey, fenc(m));
  }
}

// ---------------- kernel 2: sum exp(logit_p - m) ----------------
__global__ __launch_bounds__(256) void k_lsep(const float* __restrict__ logit_p,
                                              const unsigned* __restrict__ mkey,
                                              float* __restrict__ Sp) {
  __shared__ float sm[4];
  const int t = threadIdx.x, lane = t & 63, w = t >> 6;
  float m = fdec(*mkey);
  float v = __expf(logit_p[blockIdx.x * 256 + t] - m);
#pragma unroll
  for (int off = 32; off; off >>= 1) v += __shfl_down(v, off);
  if (lane == 0) sm[w] = v;
  __syncthreads();
  if (t == 0) unsafeAtomicAdd(Sp, sm[0] + sm[1] + sm[2] + sm[3]);
}

// ---------------- kernel 3: bf16 GEMM (K=128, async LDS, xor swizzle) + diag sumexp ----------------
__global__ __launch_bounds__(256, 2) void k_main(const unsigned short* __restrict__ A,
                                                 const unsigned short* __restrict__ B,
                                                 float* __restrict__ sumexp) {
  __shared__ __align__(16) unsigned short As[128 * 128];
  __shared__ __align__(16) unsigned short Bs[128 * 128];
  __shared__ float diag4[4][256];

  const int t = threadIdx.x;
  const int bx = blockIdx.x, by = blockIdx.y;
  const int i0 = by * 128, j0 = bx * 128;

#pragma unroll
  for (int q = 0; q < 4; ++q) diag4[q][t] = 0.0f;

  // stage whole 128x128 bf16 tiles; LDS chunk slot (t&15) holds global chunk (t&15)^(row&7)
  const char* Ag = (const char*)(A + (size_t)i0 * 128);
  const char* Bg = (const char*)(B + (size_t)j0 * 128);
  char* AsB = (char*)As;
  char* BsB = (char*)Bs;
#pragma unroll
  for (int j = 0; j < 8; ++j) {
    int rl   = j * 16 + (t >> 4);
    int c    = (t & 15) ^ (rl & 7);
    int goff = rl * 256 + c * 16;
    int loff = j * 4096 + t * 16;
    gl_lds16(Ag + goff, AsB + loff);
    gl_lds16(Bg + goff, BsB + loff);
  }

  const int lane = t & 63;
  const int w = t >> 6, wrow = w >> 1, wcol = w & 1;
  const int l15 = lane & 15, quad = lane >> 4;
  const int x7 = l15 & 7;

  f32x4 acc[4][4];
  const f32x4 zv = {0.f, 0.f, 0.f, 0.f};
#pragma unroll
  for (int r = 0; r < 4; ++r)
#pragma unroll
    for (int c = 0; c < 4; ++c) acc[r][c] = zv;

  __syncthreads();  // drains vmcnt for the async loads

  const unsigned short* Abase = As + (wrow * 64 + l15) * 128;
  const unsigned short* Bbase = Bs + (wcol * 64 + l15) * 128;

#pragma unroll
  for (int ks = 0; ks < 4; ++ks) {
    bf16x8 a[4], b[4];
    const int off = ((ks * 4 + quad) ^ x7) * 8;   // swizzled chunk -> element offset
#pragma unroll
    for (int r = 0; r < 4; ++r)
      a[r] = *reinterpret_cast<const bf16x8*>(Abase + r * 16 * 128 + off);
#pragma unroll
    for (int c = 0; c < 4; ++c)
      b[c] = *reinterpret_cast<const bf16x8*>(Bbase + c * 16 * 128 + off);
#pragma unroll
    for (int r = 0; r < 4; ++r)
#pragma unroll
      for (int c = 0; c < 4; ++c)
        acc[r][c] = __builtin_amdgcn_mfma_f32_16x16x32_bf16(a[r], b[c], acc[r][c], 0, 0, 0);
  }

  // ---- epilogue: sn is already cosine similarity (normalized inputs) ----
  const bool hasDiag = (bx == by);
  const int dbase = (wcol - wrow) * 64 + (l15 - quad * 4) + 127;

  // 64*log2(e) = 92.33248262 ; 0.25*64*log2(e) = 23.08312065
#pragma unroll
  for (int dlt = -3; dlt <= 3; ++dlt) {
#pragma unroll
    for (int g = 0; g < 4; ++g) {
      float s = 0.0f;
#pragma unroll
      for (int r = 0; r < 4; ++r) {
        int c = r + dlt;
        if (c < 0 || c > 3) continue;
        float sn = acc[r][c][g];
        float an = fmaxf(sn + 0.25f, 0.0f);
        float u  = fmaf(sn, 92.332483f, -23.083121f);
        s += exp2f(an * u);
      }
      int ld = dbase + dlt * 16 - g;
      if (hasDiag && (ld == 127)) s = 0.0f;  // true diagonal handled via logit_p
      unsafeAtomicAdd(&diag4[quad][ld], s);  // distinct addrs within a quad: no same-addr serialization
    }
  }
  __syncthreads();

  if (t < 255) {
    float v = diag4[0][t] + diag4[1][t] + diag4[2][t] + diag4[3][t];
    int d = (j0 - i0 + t - 127 + NN) & (NN - 1);
    unsafeAtomicAdd(&sumexp[d], v);
  }
}

// ---------------- kernel 4: per-diagonal softplus partial sums ----------------
__global__ __launch_bounds__(256) void k_post(const float* __restrict__ sumexp,
                                              const unsigned* __restrict__ mkey,
                                              const float* __restrict__ Sp,
                                              float* __restrict__ total) {
  __shared__ float sm[4];
  const int t = threadIdx.x, lane = t & 63, w = t >> 6;
  const int d = blockIdx.x * 256 + t;
  float lse_p = fdec(*mkey) + __logf(*Sp);
  float acc = 0.0f;
  if (d != 0) {
    float x = __logf(sumexp[d]) + lse_p;
    acc = fmaxf(x, 0.0f) + log1pf(__expf(-fabsf(x)));
  }
#pragma unroll
  for (int off = 32; off; off >>= 1) acc += __shfl_down(acc, off);
  if (lane == 0) sm[w] = acc;
  __syncthreads();
  if (t == 0) unsafeAtomicAdd(total, sm[0] + sm[1] + sm[2] + sm[3]);
}

// ---------------- kernel 5: write the scalar ----------------
__global__ void k_write(const float* __restrict__ total, float* __restrict__ out) {
  if (threadIdx.x == 0) out[0] = total[0] * (1.0f / 8191.0f);
}

// ---------------- launcher ----------------
extern "C" void kernel_launch(void* const* d_in, const int* in_sizes, int n_in,
                              void* d_out, int out_size, void* d_ws, size_t ws_size,
                              hipStream_t stream) {
  const float* enc = (const float*)d_in[0];
  const float* dec = (const float*)d_in[1];
  float* ws = (float*)d_ws;

  float*    sumexp  = ws;                          // [0 .. 8191]
  unsigned* mkey    = (unsigned*)(ws + 8192);      // ctrl
  float*    Sp      = ws + 8193;
  float*    total   = ws + 8194;
  float*    logit_p = ws + 8704;                   // [8704 .. 16895]
  unsigned* Abf     = (unsigned*)(ws + 16896);     // 8192x128 bf16 = 2 MB
  unsigned* Bbf     = (unsigned*)(ws + 16896 + 524288);
  float* out = (float*)d_out;

  hipMemsetAsync(ws, 0, (8192 + 8) * sizeof(float), stream);  // sumexp + ctrl
  k_prep<<<NN / 4, 256, 0, stream>>>(enc, dec, Abf, Bbf, logit_p, mkey);
  k_lsep<<<NN / 256, 256, 0, stream>>>(logit_p, mkey, Sp);
  dim3 grid(NN / 128, NN / 128);
  k_main<<<grid, 256, 0, stream>>>((const unsigned short*)Abf, (const unsigned short*)Bbf, sumexp);
  k_post<<<NN / 256, 256, 0, stream>>>(sumexp, mkey, Sp, total);
  k_write<<<1, 64, 0, stream>>>(total, out);
}

// Round 3
// 171.578 us; speedup vs baseline: 1.4997x; 1.4927x over previous
//
#include <hip/hip_runtime.h>
#include <hip/hip_bf16.h>

#define NN 8192

using bf16x8 = __attribute__((ext_vector_type(8))) short;
using f32x4  = __attribute__((ext_vector_type(4))) float;

// ---- async global->LDS 16B (wave-uniform base + lane*16 layout) ----
__device__ __forceinline__ void gl_lds16(const void* g, void* l) {
  __builtin_amdgcn_global_load_lds(
      (const __attribute__((address_space(1))) unsigned int*)(unsigned long long)g,
      (__attribute__((address_space(3))) unsigned int*)(unsigned int)(unsigned long long)l,
      16, 0, 0);
}

// ---------------- kernel 1: normalize rows -> bf16, logit_p, zero sumexp ----------------
__global__ __launch_bounds__(256) void k_prep(const float* __restrict__ enc,
                                              const float* __restrict__ dec,
                                              unsigned* __restrict__ Abf,
                                              unsigned* __restrict__ Bbf,
                                              float* __restrict__ logit_p,
                                              float* __restrict__ sumexp) {
  const int w = threadIdx.x >> 6, lane = threadIdx.x & 63;
  const int row = blockIdx.x * 4 + w;
  if (threadIdx.x < 4) sumexp[blockIdx.x * 4 + threadIdx.x] = 0.0f;
  float2 ev = reinterpret_cast<const float2*>(enc)[row * 64 + lane];
  float2 dv = reinterpret_cast<const float2*>(dec)[row * 64 + lane];
  float se = ev.x * ev.x + ev.y * ev.y;
  float sd = dv.x * dv.x + dv.y * dv.y;
  float sp = ev.x * dv.x + ev.y * dv.y;
#pragma unroll
  for (int off = 1; off < 64; off <<= 1) {
    se += __shfl_xor(se, off);
    sd += __shfl_xor(sd, off);
    sp += __shfl_xor(sp, off);
  }
  float ie = rsqrtf(se), id = rsqrtf(sd);
  union { __hip_bfloat162 h; unsigned u; } pa, pb;
  pa.h = __float22bfloat162_rn(make_float2(ev.x * ie, ev.y * ie));
  pb.h = __float22bfloat162_rn(make_float2(dv.x * id, dv.y * id));
  Abf[row * 64 + lane] = pa.u;
  Bbf[row * 64 + lane] = pb.u;
  if (lane == 0) {
    float en = se * ie, dn = sd * id;                 // sqrt via x*rsqrt(x)
    float s  = sp / (en * dn + 1e-5f);
    logit_p[row] = -fmaxf(1.25f - s, 0.0f) * (s - 0.75f) * 64.0f;
  }
}

// ---------------- kernel 2: bf16 GEMM + collision-free diagonal reduce ----------------
__global__ __launch_bounds__(256, 2) void k_main(const unsigned short* __restrict__ A,
                                                 const unsigned short* __restrict__ B,
                                                 float* __restrict__ sumexp) {
  __shared__ __align__(16) unsigned short As[128 * 128];
  __shared__ __align__(16) unsigned short Bs[128 * 128];
  __shared__ float part[4][256];   // per-wave private diagonal partials

  const int t = threadIdx.x;
  const int bx = blockIdx.x, by = blockIdx.y;
  const int i0 = by * 128, j0 = bx * 128;

#pragma unroll
  for (int q = 0; q < 4; ++q) part[q][t] = 0.0f;

  // stage whole 128x128 bf16 tiles; LDS chunk slot (t&15) holds global chunk (t&15)^(row&7)
  const char* Ag = (const char*)(A + (size_t)i0 * 128);
  const char* Bg = (const char*)(B + (size_t)j0 * 128);
  char* AsB = (char*)As;
  char* BsB = (char*)Bs;
#pragma unroll
  for (int j = 0; j < 8; ++j) {
    int rl   = j * 16 + (t >> 4);
    int c    = (t & 15) ^ (rl & 7);
    int goff = rl * 256 + c * 16;
    int loff = j * 4096 + t * 16;
    gl_lds16(Ag + goff, AsB + loff);
    gl_lds16(Bg + goff, BsB + loff);
  }

  const int lane = t & 63;
  const int w = t >> 6, wrow = w >> 1, wcol = w & 1;
  const int l15 = lane & 15, quad = lane >> 4;
  const int x7 = l15 & 7;

  f32x4 acc[4][4];
  const f32x4 zv = {0.f, 0.f, 0.f, 0.f};
#pragma unroll
  for (int r = 0; r < 4; ++r)
#pragma unroll
    for (int c = 0; c < 4; ++c) acc[r][c] = zv;

  __syncthreads();  // drains vmcnt for the async loads

  const unsigned short* Abase = As + (wrow * 64 + l15) * 128;
  const unsigned short* Bbase = Bs + (wcol * 64 + l15) * 128;

#pragma unroll
  for (int ks = 0; ks < 4; ++ks) {
    bf16x8 a[4], b[4];
    const int off = ((ks * 4 + quad) ^ x7) * 8;   // swizzled chunk -> element offset
#pragma unroll
    for (int r = 0; r < 4; ++r)
      a[r] = *reinterpret_cast<const bf16x8*>(Abase + r * 16 * 128 + off);
#pragma unroll
    for (int c = 0; c < 4; ++c)
      b[c] = *reinterpret_cast<const bf16x8*>(Bbase + c * 16 * 128 + off);
#pragma unroll
    for (int r = 0; r < 4; ++r)
#pragma unroll
      for (int c = 0; c < 4; ++c)
        acc[r][c] = __builtin_amdgcn_mfma_f32_16x16x32_bf16(a[r], b[c], acc[r][c], 0, 0, 0);
  }

  // ---- epilogue: circle-loss exp + per-diagonal reduce, no same-address LDS atomics ----
  // element (r,c,g) diagonal: ld = (wcol-wrow)*64 + 127 + (c-r)*16 - g + (l15 - 4*quad)
  // lanes sharing ld (same v = l15-4*quad) sit 20 lanes apart -> 2-step shfl tree
  const bool hasDiag = (bx == by);
  const int  Qoff = (wcol - wrow) * 64 + 127;
  const int  v    = l15 - quad * 4;
  const bool leader = (quad == 0) || (l15 <= 3);
  const bool ok1 = (l15 <= 11) && (quad <= 2);
  const bool ok2 = (l15 <= 7)  && (quad <= 1);

  // 64*log2(e) = 92.33248262 ; 0.25*64*log2(e) = 23.08312065
#pragma unroll
  for (int dlt = -3; dlt <= 3; ++dlt) {
#pragma unroll
    for (int g = 0; g < 4; ++g) {
      float s = 0.0f;
#pragma unroll
      for (int r = 0; r < 4; ++r) {
        int c = r + dlt;
        if (c < 0 || c > 3) continue;
        float sn = acc[r][c][g];
        float an = fmaxf(sn + 0.25f, 0.0f);
        float u  = fmaf(sn, 92.332483f, -23.083121f);
        s += exp2f(an * u);
      }
      int ld = Qoff + dlt * 16 - g + v;
      if (hasDiag && (ld == 127)) s = 0.0f;   // true diagonal handled via logit_p
      float t1 = __shfl_down(s, 20); s += ok1 ? t1 : 0.0f;  // + member (q+1)
      float t2 = __shfl_down(s, 40); s += ok2 ? t2 : 0.0f;  // + members (q+2,q+3)
      if (leader) unsafeAtomicAdd(&part[w][ld], s);  // distinct ld per leader: collision-free
    }
  }
  __syncthreads();

  if (t < 255) {
    float vv = part[0][t] + part[1][t] + part[2][t] + part[3][t];
    int d = (j0 - i0 + t - 127 + NN) & (NN - 1);
    unsafeAtomicAdd(&sumexp[d], vv);
  }
}

// ---------------- kernel 3: lse_p + softplus mean (one block, 1024 threads) ----------------
__global__ __launch_bounds__(1024) void k_fin(const float* __restrict__ logit_p,
                                              const float* __restrict__ sumexp,
                                              float* __restrict__ out) {
  __shared__ float sm[16];
  const int t = threadIdx.x, lane = t & 63, w = t >> 6;

  // phase 1: max of logit_p
  float m = -3.0e38f;
  for (int i = t; i < NN; i += 1024) m = fmaxf(m, logit_p[i]);
#pragma unroll
  for (int off = 32; off; off >>= 1) m = fmaxf(m, __shfl_down(m, off));
  if (lane == 0) sm[w] = m;
  __syncthreads();
  m = sm[0];
#pragma unroll
  for (int k = 1; k < 16; ++k) m = fmaxf(m, sm[k]);
  __syncthreads();

  // phase 2: sum exp(logit_p - m) -> lse_p
  float s = 0.0f;
  for (int i = t; i < NN; i += 1024) s += __expf(logit_p[i] - m);
#pragma unroll
  for (int off = 32; off; off >>= 1) s += __shfl_down(s, off);
  if (lane == 0) sm[w] = s;
  __syncthreads();
  s = 0.0f;
#pragma unroll
  for (int k = 0; k < 16; ++k) s += sm[k];
  float lse_p = m + __logf(s);
  __syncthreads();

  // phase 3: mean over d=1..N-1 of softplus(log(sumexp[d]) + lse_p)
  float acc = 0.0f;
  for (int i = t; i < NN; i += 1024) {
    if (i == 0) continue;
    float x = __logf(sumexp[i]) + lse_p;
    acc += fmaxf(x, 0.0f) + log1pf(__expf(-fabsf(x)));
  }
#pragma unroll
  for (int off = 32; off; off >>= 1) acc += __shfl_down(acc, off);
  if (lane == 0) sm[w] = acc;
  __syncthreads();
  if (t == 0) {
    float tot = 0.0f;
#pragma unroll
    for (int k = 0; k < 16; ++k) tot += sm[k];
    out[0] = tot * (1.0f / 8191.0f);
  }
}

// ---------------- launcher ----------------
extern "C" void kernel_launch(void* const* d_in, const int* in_sizes, int n_in,
                              void* d_out, int out_size, void* d_ws, size_t ws_size,
                              hipStream_t stream) {
  const float* enc = (const float*)d_in[0];
  const float* dec = (const float*)d_in[1];
  float* ws = (float*)d_ws;

  float*    sumexp  = ws;                          // 8192
  float*    logit_p = ws + 8192;                   // 8192
  unsigned* Abf     = (unsigned*)(ws + 16384);     // 8192x128 bf16 = 2 MB
  unsigned* Bbf     = (unsigned*)(ws + 16384 + 524288);
  float* out = (float*)d_out;

  k_prep<<<NN / 4, 256, 0, stream>>>(enc, dec, Abf, Bbf, logit_p, sumexp);
  dim3 grid(NN / 128, NN / 128);
  k_main<<<grid, 256, 0, stream>>>((const unsigned short*)Abf, (const unsigned short*)Bbf, sumexp);
  k_fin<<<1, 1024, 0, stream>>>(logit_p, sumexp, out);
}

// Round 4
// 165.636 us; speedup vs baseline: 1.5535x; 1.0359x over previous
//
#include <hip/hip_runtime.h>
#include <hip/hip_bf16.h>

#define NN 8192

using bf16x8 = __attribute__((ext_vector_type(8))) short;
using f32x4  = __attribute__((ext_vector_type(4))) float;

// ---- async global->LDS 16B (wave-uniform base + lane*16 layout) ----
__device__ __forceinline__ void gl_lds16(const void* g, void* l) {
  __builtin_amdgcn_global_load_lds(
      (const __attribute__((address_space(1))) unsigned int*)(unsigned long long)g,
      (__attribute__((address_space(3))) unsigned int*)(unsigned int)(unsigned long long)l,
      16, 0, 0);
}

// ---------------- kernel 1: normalize rows -> bf16, logit_p, zero bandsum ----------------
__global__ __launch_bounds__(256) void k_prep(const float* __restrict__ enc,
                                              const float* __restrict__ dec,
                                              unsigned* __restrict__ Abf,
                                              unsigned* __restrict__ Bbf,
                                              float* __restrict__ logit_p,
                                              float* __restrict__ bandsum) {
  const int w = threadIdx.x >> 6, lane = threadIdx.x & 63;
  const int row = blockIdx.x * 4 + w;
  const int tid = blockIdx.x * 256 + threadIdx.x;
  if (tid < 64 * 256) bandsum[tid] = 0.0f;
  float2 ev = reinterpret_cast<const float2*>(enc)[row * 64 + lane];
  float2 dv = reinterpret_cast<const float2*>(dec)[row * 64 + lane];
  float se = ev.x * ev.x + ev.y * ev.y;
  float sd = dv.x * dv.x + dv.y * dv.y;
  float sp = ev.x * dv.x + ev.y * dv.y;
#pragma unroll
  for (int off = 1; off < 64; off <<= 1) {
    se += __shfl_xor(se, off);
    sd += __shfl_xor(sd, off);
    sp += __shfl_xor(sp, off);
  }
  float ie = rsqrtf(se), id = rsqrtf(sd);
  union { __hip_bfloat162 h; unsigned u; } pa, pb;
  pa.h = __float22bfloat162_rn(make_float2(ev.x * ie, ev.y * ie));
  pb.h = __float22bfloat162_rn(make_float2(dv.x * id, dv.y * id));
  Abf[row * 64 + lane] = pa.u;
  Bbf[row * 64 + lane] = pb.u;
  if (lane == 0) {
    float en = se * ie, dn = sd * id;                 // sqrt via x*rsqrt(x)
    float s  = sp / (en * dn + 1e-5f);
    logit_p[row] = -fmaxf(1.25f - s, 0.0f) * (s - 0.75f) * 64.0f;
  }
}

// ---------------- kernel 2: banded bf16 GEMM + in-LDS diagonal accumulation ----------------
// grid = (64 tile-diagonal bands) x (8 splits); each block sweeps 8 tiles of its band.
__global__ __launch_bounds__(256, 2) void k_main(const unsigned short* __restrict__ A,
                                                 const unsigned short* __restrict__ B,
                                                 float* __restrict__ bandsum) {
  __shared__ __align__(16) unsigned short As[128 * 128];
  __shared__ __align__(16) unsigned short Bs[128 * 128];
  __shared__ float part[4][256];   // per-wave private diagonal partials (across all 8 tiles)

  const int t  = threadIdx.x;
  const int T  = blockIdx.x;   // tile-diagonal band: all tiles with (bx-by)&63 == T
  const int sp = blockIdx.y;   // split along the band

#pragma unroll
  for (int q = 0; q < 4; ++q) part[q][t] = 0.0f;

  const int lane = t & 63;
  const int w = t >> 6, wrow = w >> 1, wcol = w & 1;
  const int l15 = lane & 15, quad = lane >> 4;
  const int x7 = l15 & 7;

  const unsigned short* Abase = As + (wrow * 64 + l15) * 128;
  const unsigned short* Bbase = Bs + (wcol * 64 + l15) * 128;

  // epilogue lane constants
  const bool hasDiag = (T == 0);
  const int  Qoff = (wcol - wrow) * 64 + 127;
  const int  v    = l15 - quad * 4;
  const bool leader = (quad == 0) || (l15 <= 3);
  const bool ok1 = (l15 <= 11) && (quad <= 2);
  const bool ok2 = (l15 <= 7)  && (quad <= 1);

  char* AsB = (char*)As;
  char* BsB = (char*)Bs;

  for (int it = 0; it < 8; ++it) {
    const int by = sp * 8 + it;
    const int bx = (by + T) & 63;
    const char* Ag = (const char*)(A + (size_t)by * 128 * 128);
    const char* Bg = (const char*)(B + (size_t)bx * 128 * 128);

    if (it) __syncthreads();   // previous tile's ds_reads done before restage
    // stage 128x128 bf16 tiles; LDS chunk slot (t&15) holds global chunk (t&15)^(row&7)
#pragma unroll
    for (int j = 0; j < 8; ++j) {
      int rl   = j * 16 + (t >> 4);
      int c    = (t & 15) ^ (rl & 7);
      int goff = rl * 256 + c * 16;
      int loff = j * 4096 + t * 16;
      gl_lds16(Ag + goff, AsB + loff);
      gl_lds16(Bg + goff, BsB + loff);
    }
    __syncthreads();           // barrier drains vmcnt: staged data visible

    f32x4 acc[4][4];
    const f32x4 zv = {0.f, 0.f, 0.f, 0.f};
#pragma unroll
    for (int r = 0; r < 4; ++r)
#pragma unroll
      for (int c = 0; c < 4; ++c) acc[r][c] = zv;

#pragma unroll
    for (int ks = 0; ks < 4; ++ks) {
      bf16x8 a[4], b[4];
      const int off = ((ks * 4 + quad) ^ x7) * 8;   // swizzled chunk -> element offset
#pragma unroll
      for (int r = 0; r < 4; ++r)
        a[r] = *reinterpret_cast<const bf16x8*>(Abase + r * 16 * 128 + off);
#pragma unroll
      for (int c = 0; c < 4; ++c)
        b[c] = *reinterpret_cast<const bf16x8*>(Bbase + c * 16 * 128 + off);
#pragma unroll
      for (int r = 0; r < 4; ++r)
#pragma unroll
        for (int c = 0; c < 4; ++c)
          acc[r][c] = __builtin_amdgcn_mfma_f32_16x16x32_bf16(a[r], b[c], acc[r][c], 0, 0, 0);
    }

    // ---- epilogue: exp + per-diagonal reduce into per-wave LDS rows ----
    // 64*log2(e) = 92.33248262 ; 0.25*64*log2(e) = 23.08312065
#pragma unroll
    for (int dlt = -3; dlt <= 3; ++dlt) {
#pragma unroll
      for (int g = 0; g < 4; ++g) {
        float s = 0.0f;
#pragma unroll
        for (int r = 0; r < 4; ++r) {
          int c = r + dlt;
          if (c < 0 || c > 3) continue;
          float sn = acc[r][c][g];
          float an = fmaxf(sn + 0.25f, 0.0f);
          float u  = fmaf(sn, 92.332483f, -23.083121f);
          s += exp2f(an * u);
        }
        int ld = Qoff + dlt * 16 - g + v;
        if (hasDiag && (ld == 127)) s = 0.0f;   // true diagonal handled via logit_p
        float t1 = __shfl_down(s, 20); s += ok1 ? t1 : 0.0f;  // partner quad+1
        float t2 = __shfl_down(s, 40); s += ok2 ? t2 : 0.0f;  // partners quad+2, quad+3
        if (leader) unsafeAtomicAdd(&part[w][ld], s);  // distinct ld per leader: collision-free
      }
    }
  }
  __syncthreads();

  // single flush per block: 255 atomics onto this band's row (8 writers/address total)
  if (t < 255) {
    float vv = part[0][t] + part[1][t] + part[2][t] + part[3][t];
    unsafeAtomicAdd(&bandsum[T * 256 + t], vv);
  }
}

// ---------------- kernel 3: lse_p + softplus mean (one block, 1024 threads) ----------------
__global__ __launch_bounds__(1024) void k_fin(const float* __restrict__ logit_p,
                                              const float* __restrict__ bandsum,
                                              float* __restrict__ out) {
  __shared__ float sm[16];
  const int t = threadIdx.x, lane = t & 63, w = t >> 6;

  // phase 1: max of logit_p
  float m = -3.0e38f;
  for (int i = t; i < NN; i += 1024) m = fmaxf(m, logit_p[i]);
#pragma unroll
  for (int off = 32; off; off >>= 1) m = fmaxf(m, __shfl_down(m, off));
  if (lane == 0) sm[w] = m;
  __syncthreads();
  m = sm[0];
#pragma unroll
  for (int k = 1; k < 16; ++k) m = fmaxf(m, sm[k]);
  __syncthreads();

  // phase 2: sum exp(logit_p - m) -> lse_p
  float s = 0.0f;
  for (int i = t; i < NN; i += 1024) s += __expf(logit_p[i] - m);
#pragma unroll
  for (int off = 32; off; off >>= 1) s += __shfl_down(s, off);
  if (lane == 0) sm[w] = s;
  __syncthreads();
  s = 0.0f;
#pragma unroll
  for (int k = 0; k < 16; ++k) s += sm[k];
  float lse_p = m + __logf(s);
  __syncthreads();

  // phase 3: per-diagonal band gather + softplus mean over d=1..N-1
  // band T covers d = (T*128 + o - 127) mod 8192, o in [0,254]
  float acc = 0.0f;
  for (int d = t; d < NN; d += 1024) {
    if (d == 0) continue;
    int Ta = d >> 7;
    float se = bandsum[Ta * 256 + (d & 127) + 127];
    if (d & 127) {
      int Tb = (Ta + 1) & 63;
      se += bandsum[Tb * 256 + (d & 127) - 1];
    }
    float x = __logf(se) + lse_p;
    acc += fmaxf(x, 0.0f) + __logf(1.0f + __expf(-fabsf(x)));  // cheap exact-enough softplus
  }
#pragma unroll
  for (int off = 32; off; off >>= 1) acc += __shfl_down(acc, off);
  if (lane == 0) sm[w] = acc;
  __syncthreads();
  if (t == 0) {
    float tot = 0.0f;
#pragma unroll
    for (int k = 0; k < 16; ++k) tot += sm[k];
    out[0] = tot * (1.0f / 8191.0f);
  }
}

// ---------------- launcher ----------------
extern "C" void kernel_launch(void* const* d_in, const int* in_sizes, int n_in,
                              void* d_out, int out_size, void* d_ws, size_t ws_size,
                              hipStream_t stream) {
  const float* enc = (const float*)d_in[0];
  const float* dec = (const float*)d_in[1];
  float* ws = (float*)d_ws;

  float*    logit_p = ws;                          // 8192
  float*    bandsum = ws + 8192;                   // 64*256 = 16384
  unsigned* Abf     = (unsigned*)(ws + 8192 + 16384);   // 8192x128 bf16 = 2 MB
  unsigned* Bbf     = Abf + 524288;
  float* out = (float*)d_out;

  k_prep<<<NN / 4, 256, 0, stream>>>(enc, dec, Abf, Bbf, logit_p, bandsum);
  dim3 grid(64, 8);
  k_main<<<grid, 256, 0, stream>>>((const unsigned short*)Abf, (const unsigned short*)Bbf, bandsum);
  k_fin<<<1, 1024, 0, stream>>>(logit_p, bandsum, out);
}

// Round 6
// 108.152 us; speedup vs baseline: 2.3791x; 1.5315x over previous
//
#include <hip/hip_runtime.h>
#include <hip/hip_bf16.h>

#define NN 8192

using bf16x8 = __attribute__((ext_vector_type(8))) short;
using f32x4  = __attribute__((ext_vector_type(4))) float;

// ---- async global->LDS 16B (wave-uniform base + lane*16 layout) ----
__device__ __forceinline__ void gl_lds16(const void* g, void* l) {
  __builtin_amdgcn_global_load_lds(
      (const __attribute__((address_space(1))) unsigned int*)(unsigned long long)g,
      (__attribute__((address_space(3))) unsigned int*)(unsigned int)(unsigned long long)l,
      16, 0, 0);
}

// ---------------- kernel 1: normalize rows -> bf16, logit_p, zero bandsum ----------------
// 16-lane row groups: each block of 256 handles 16 rows.
__global__ __launch_bounds__(256) void k_prep(const float* __restrict__ enc,
                                              const float* __restrict__ dec,
                                              unsigned* __restrict__ Abf,
                                              unsigned* __restrict__ Bbf,
                                              float* __restrict__ logit_p,
                                              float* __restrict__ bandsum) {
  const int t = threadIdx.x;
  const int l16 = t & 15;
  const int row = blockIdx.x * 16 + (t >> 4);
  const int tid = blockIdx.x * 256 + t;
  if (tid < 64 * 256) bandsum[tid] = 0.0f;

  const float4* e4 = reinterpret_cast<const float4*>(enc) + (size_t)row * 32 + l16 * 2;
  const float4* d4 = reinterpret_cast<const float4*>(dec) + (size_t)row * 32 + l16 * 2;
  float4 e0 = e4[0], e1 = e4[1];
  float4 d0 = d4[0], d1 = d4[1];

  float se = e0.x*e0.x + e0.y*e0.y + e0.z*e0.z + e0.w*e0.w
           + e1.x*e1.x + e1.y*e1.y + e1.z*e1.z + e1.w*e1.w;
  float sd = d0.x*d0.x + d0.y*d0.y + d0.z*d0.z + d0.w*d0.w
           + d1.x*d1.x + d1.y*d1.y + d1.z*d1.z + d1.w*d1.w;
  float sp = e0.x*d0.x + e0.y*d0.y + e0.z*d0.z + e0.w*d0.w
           + e1.x*d1.x + e1.y*d1.y + e1.z*d1.z + e1.w*d1.w;
#pragma unroll
  for (int off = 1; off < 16; off <<= 1) {
    se += __shfl_xor(se, off);
    sd += __shfl_xor(sd, off);
    sp += __shfl_xor(sp, off);
  }
  float ie = rsqrtf(se), id = rsqrtf(sd);

  union { __hip_bfloat162 h; unsigned u; } p;
  uint4 ua, ub;
  p.h = __float22bfloat162_rn(make_float2(e0.x * ie, e0.y * ie)); ua.x = p.u;
  p.h = __float22bfloat162_rn(make_float2(e0.z * ie, e0.w * ie)); ua.y = p.u;
  p.h = __float22bfloat162_rn(make_float2(e1.x * ie, e1.y * ie)); ua.z = p.u;
  p.h = __float22bfloat162_rn(make_float2(e1.z * ie, e1.w * ie)); ua.w = p.u;
  p.h = __float22bfloat162_rn(make_float2(d0.x * id, d0.y * id)); ub.x = p.u;
  p.h = __float22bfloat162_rn(make_float2(d0.z * id, d0.w * id)); ub.y = p.u;
  p.h = __float22bfloat162_rn(make_float2(d1.x * id, d1.y * id)); ub.z = p.u;
  p.h = __float22bfloat162_rn(make_float2(d1.z * id, d1.w * id)); ub.w = p.u;
  reinterpret_cast<uint4*>(Abf)[(size_t)row * 16 + l16] = ua;
  reinterpret_cast<uint4*>(Bbf)[(size_t)row * 16 + l16] = ub;

  if (l16 == 0) {
    float en = se * ie, dn = sd * id;                 // sqrt via x*rsqrt(x)
    float s  = sp / (en * dn + 1e-5f);
    logit_p[row] = -fmaxf(1.25f - s, 0.0f) * (s - 0.75f) * 64.0f;
  }
}

// ---------------- kernel 2: banded bf16 GEMM, diagonal sums in registers ----------------
// grid = (64 bands) x (8 splits); each block sweeps 8 tiles, accumulating 28
// per-lane diagonal partials in registers; single shfl+LDS+global flush at end.
__global__ __launch_bounds__(256, 2) void k_main(const unsigned short* __restrict__ A,
                                                 const unsigned short* __restrict__ B,
                                                 float* __restrict__ bandsum) {
  __shared__ __align__(16) unsigned short As[128 * 128];
  __shared__ __align__(16) unsigned short Bs[128 * 128];
  __shared__ float part[4][256];

  const int t  = threadIdx.x;
  const int T  = blockIdx.x;   // band: tiles with (bx-by)&63 == T
  const int sp = blockIdx.y;   // split along the band

#pragma unroll
  for (int q = 0; q < 4; ++q) part[q][t] = 0.0f;

  const int lane = t & 63;
  const int w = t >> 6, wrow = w >> 1, wcol = w & 1;
  const int l15 = lane & 15, quad = lane >> 4;
  const int x7 = l15 & 7;

  const unsigned short* Abase = As + (wrow * 64 + l15) * 128;
  const unsigned short* Bbase = Bs + (wcol * 64 + l15) * 128;
  char* AsB = (char*)As;
  char* BsB = (char*)Bs;

  // persistent per-lane diagonal accumulators, one per (dlt,g)
  float dreg[28];
#pragma unroll
  for (int i = 0; i < 28; ++i) dreg[i] = 0.0f;

  const int rl_lo = t >> 4;           // row-within-16
  const int cch   = t & 15;           // chunk slot
  // stage tile 0
  {
    const int by = sp * 8;
    const int bx = (by + T) & 63;
    const char* Ag = (const char*)(A + (size_t)by * 128 * 128);
    const char* Bg = (const char*)(B + (size_t)bx * 128 * 128);
#pragma unroll
    for (int j = 0; j < 8; ++j) {
      int rl   = j * 16 + rl_lo;
      int c    = cch ^ (rl & 7);
      int goff = rl * 256 + c * 16;
      int loff = j * 4096 + t * 16;
      gl_lds16(Ag + goff, AsB + loff);
      gl_lds16(Bg + goff, BsB + loff);
    }
  }
  __syncthreads();   // drain vmcnt: tile 0 staged

  for (int it = 0; it < 8; ++it) {
    f32x4 acc[4][4];
    const f32x4 zv = {0.f, 0.f, 0.f, 0.f};
#pragma unroll
    for (int r = 0; r < 4; ++r)
#pragma unroll
      for (int c = 0; c < 4; ++c) acc[r][c] = zv;

#pragma unroll
    for (int ks = 0; ks < 4; ++ks) {
      bf16x8 a[4], b[4];
      const int off = ((ks * 4 + quad) ^ x7) * 8;   // swizzled chunk -> element offset
#pragma unroll
      for (int r = 0; r < 4; ++r)
        a[r] = *reinterpret_cast<const bf16x8*>(Abase + r * 16 * 128 + off);
#pragma unroll
      for (int c = 0; c < 4; ++c)
        b[c] = *reinterpret_cast<const bf16x8*>(Bbase + c * 16 * 128 + off);
#pragma unroll
      for (int r = 0; r < 4; ++r)
#pragma unroll
        for (int c = 0; c < 4; ++c)
          acc[r][c] = __builtin_amdgcn_mfma_f32_16x16x32_bf16(a[r], b[c], acc[r][c], 0, 0, 0);
    }

    __syncthreads();   // all ds_reads of this tile done -> LDS reusable

    if (it < 7) {      // issue next tile's async stage; flies under the epilogue
      const int by = sp * 8 + it + 1;
      const int bx = (by + T) & 63;
      const char* Ag = (const char*)(A + (size_t)by * 128 * 128);
      const char* Bg = (const char*)(B + (size_t)bx * 128 * 128);
#pragma unroll
      for (int j = 0; j < 8; ++j) {
        int rl   = j * 16 + rl_lo;
        int c    = cch ^ (rl & 7);
        int goff = rl * 256 + c * 16;
        int loff = j * 4096 + t * 16;
        gl_lds16(Ag + goff, AsB + loff);
        gl_lds16(Bg + goff, BsB + loff);
      }
    }

    // ---- epilogue: pure register math, no shfl/atomics ----
    // 64*log2(e) = 92.33248262 ; 0.25*64*log2(e) = 23.08312065
#pragma unroll
    for (int dlt = -3; dlt <= 3; ++dlt) {
#pragma unroll
      for (int g = 0; g < 4; ++g) {
        float s = 0.0f;
#pragma unroll
        for (int r = 0; r < 4; ++r) {
          int c = r + dlt;
          if (c < 0 || c > 3) continue;
          float sn = acc[r][c][g];
          float an = fmaxf(sn + 0.25f, 0.0f);
          float u  = fmaf(sn, 92.332483f, -23.083121f);
          s += exp2f(an * u);
        }
        dreg[(dlt + 3) * 4 + g] += s;
      }
    }

    __syncthreads();   // drain vmcnt: next tile staged (and epilogue regs-only)
  }

  // ---- single flush: shfl tree over the 4-lane collision groups, then LDS, then global ----
  const int  Qoff = (wcol - wrow) * 64 + 127;
  const int  v    = l15 - quad * 4;
  const bool leader = (quad == 0) || (l15 <= 3);
  const bool ok1 = (l15 <= 11) && (quad <= 2);
  const bool ok2 = (l15 <= 7)  && (quad <= 1);

#pragma unroll
  for (int dlt = -3; dlt <= 3; ++dlt) {
#pragma unroll
    for (int g = 0; g < 4; ++g) {
      float s = dreg[(dlt + 3) * 4 + g];
      float t1 = __shfl_down(s, 20); s += ok1 ? t1 : 0.0f;  // partner quad+1
      float t2 = __shfl_down(s, 40); s += ok2 ? t2 : 0.0f;  // partners quad+2, quad+3
      int ld = Qoff + dlt * 16 - g + v;
      if (leader) unsafeAtomicAdd(&part[w][ld], s);         // distinct ld per leader
    }
  }
  __syncthreads();

  // band-0 slot 127 corresponds to d=0 only, which k_fin skips -> no masking needed
  if (t < 255) {
    float vv = part[0][t] + part[1][t] + part[2][t] + part[3][t];
    unsafeAtomicAdd(&bandsum[T * 256 + t], vv);
  }
}

// ---------------- kernel 3: lse_p + softplus mean (one block, 1024 threads) ----------------
__global__ __launch_bounds__(1024) void k_fin(const float* __restrict__ logit_p,
                                              const float* __restrict__ bandsum,
                                              float* __restrict__ out) {
  __shared__ float sm[16];
  const int t = threadIdx.x, lane = t & 63, w = t >> 6;

  // phase 1: max of logit_p
  float m = -3.0e38f;
  for (int i = t; i < NN; i += 1024) m = fmaxf(m, logit_p[i]);
#pragma unroll
  for (int off = 32; off; off >>= 1) m = fmaxf(m, __shfl_down(m, off));
  if (lane == 0) sm[w] = m;
  __syncthreads();
  m = sm[0];
#pragma unroll
  for (int k = 1; k < 16; ++k) m = fmaxf(m, sm[k]);
  __syncthreads();

  // phase 2: sum exp(logit_p - m) -> lse_p
  float s = 0.0f;
  for (int i = t; i < NN; i += 1024) s += __expf(logit_p[i] - m);
#pragma unroll
  for (int off = 32; off; off >>= 1) s += __shfl_down(s, off);
  if (lane == 0) sm[w] = s;
  __syncthreads();
  s = 0.0f;
#pragma unroll
  for (int k = 0; k < 16; ++k) s += sm[k];
  float lse_p = m + __logf(s);
  __syncthreads();

  // phase 3: per-diagonal band gather + softplus mean over d=1..N-1
  float acc = 0.0f;
  for (int d = t; d < NN; d += 1024) {
    if (d == 0) continue;
    int Ta = d >> 7;
    float se = bandsum[Ta * 256 + (d & 127) + 127];
    if (d & 127) {
      int Tb = (Ta + 1) & 63;
      se += bandsum[Tb * 256 + (d & 127) - 1];
    }
    float x = __logf(se) + lse_p;
    acc += fmaxf(x, 0.0f) + __logf(1.0f + __expf(-fabsf(x)));
  }
#pragma unroll
  for (int off = 32; off; off >>= 1) acc += __shfl_down(acc, off);
  if (lane == 0) sm[w] = acc;
  __syncthreads();
  if (t == 0) {
    float tot = 0.0f;
#pragma unroll
    for (int k = 0; k < 16; ++k) tot += sm[k];
    out[0] = tot * (1.0f / 8191.0f);
  }
}

// ---------------- launcher ----------------
extern "C" void kernel_launch(void* const* d_in, const int* in_sizes, int n_in,
                              void* d_out, int out_size, void* d_ws, size_t ws_size,
                              hipStream_t stream) {
  const float* enc = (const float*)d_in[0];
  const float* dec = (const float*)d_in[1];
  float* ws = (float*)d_ws;

  float*    logit_p = ws;                               // 8192
  float*    bandsum = ws + 8192;                        // 64*256
  unsigned* Abf     = (unsigned*)(ws + 8192 + 16384);   // 8192x128 bf16 = 2 MB
  unsigned* Bbf     = Abf + 524288;
  float* out = (float*)d_out;

  k_prep<<<NN / 16, 256, 0, stream>>>(enc, dec, Abf, Bbf, logit_p, bandsum);
  dim3 grid(64, 8);
  k_main<<<grid, 256, 0, stream>>>((const unsigned short*)Abf, (const unsigned short*)Bbf, bandsum);
  k_fin<<<1, 1024, 0, stream>>>(logit_p, bandsum, out);
}